// Round 8
// baseline (558.775 us; speedup 1.0000x reference)
//
#include <hip/hip_runtime.h>

#define NB 256   // batch
#define NT 512   // time steps
#define ND 128   // input dim
#define NU 128   // hidden dim
#define NC 64    // classes
#define NM (NB * NT)   // 131072 flat rows
#define YP 136         // LDS row pitch in halfs for k1/k3 weight tiles
#define SCL 2.8853900817779268f  // 2*log2(e): folds tanh 2x arg-scale + e^x -> 2^x

typedef _Float16 half2v __attribute__((ext_vector_type(2)));
typedef _Float16 half4v __attribute__((ext_vector_type(4)));
typedef _Float16 half8v __attribute__((ext_vector_type(8)));
typedef float f32x4 __attribute__((ext_vector_type(4)));
typedef float v2f __attribute__((ext_vector_type(2)));

#define MFMA(a, b, c) __builtin_amdgcn_mfma_f32_16x16x32_f16((a), (b), (c), 0, 0, 0)

// packed f32x2 -> f16x2
__device__ __forceinline__ half2v pk2(float a, float b) {
  return __builtin_bit_cast(half2v, __builtin_amdgcn_cvt_pkrtz(a, b));
}

// tanh from pre-scaled s = 2x*log2e: tanh(x) = 1 - 2/(2^s + 1); exact limits.
__device__ __forceinline__ float tanh_s(float s) {
  float e = __builtin_amdgcn_exp2f(s);
  return fmaf(-2.0f, __builtin_amdgcn_rcpf(e + 1.0f), 1.0f);
}
// y' = th + tanh(s) - 1 = th - 2/(2^s+1): the "-1" shift lets the constant
// 1-vector be folded into the next GEMM's bias via column sums of W2/Wc.
__device__ __forceinline__ float ym1(float s, float th) {
  float e = __builtin_amdgcn_exp2f(s);
  return fmaf(-2.0f, __builtin_amdgcn_rcpf(e + 1.0f), th);
}

// LDS-only barrier (no vmem drain -> prefetches/stores stay in flight).
__device__ __forceinline__ void wg_barrier() {
  asm volatile("s_waitcnt lgkmcnt(0)\n\ts_barrier" ::: "memory");
}

// ===================== K1: THp = tanh(x @ W1 + b1) -> f16, PERMUTED =====================
// Stores hidden dim permuted p = 32q + 4ht + i  (h = 16ht + 4q + i) so k2's
// per-lane per-step th is 4 contiguous b128 loads.
__global__ __launch_bounds__(256, 1) void k1_inproj(
    const float* __restrict__ x, const float* __restrict__ W1,
    const float* __restrict__ b1v, _Float16* __restrict__ THp)
{
  __shared__ _Float16 W1T[ND * YP];  // W1^T[n][k], pre-scaled by SCL
  const int tid = (int)threadIdx.x;
  for (int i = tid; i < ND * NU / 2; i += 256) {
    int n = i & 127, kh = i >> 7;
    half2v p = {(_Float16)(SCL * W1[(size_t)(2 * kh) * NU + n]),
                (_Float16)(SCL * W1[(size_t)(2 * kh + 1) * NU + n])};
    *(half2v*)&W1T[n * YP + 2 * kh] = p;
  }
  __syncthreads();

  const int L = tid & 63, wv = tid >> 6;
  const int v = L & 15, q = L >> 4;
  const int m0 = (int)blockIdx.x * 64 + wv * 16;

  const float* xr = x + (size_t)(m0 + v) * ND + 8 * q;
  half8v xf[4];
#pragma unroll
  for (int kk = 0; kk < 4; ++kk) {
    float4 a = *(const float4*)(xr + 32 * kk);
    float4 b = *(const float4*)(xr + 32 * kk + 4);
    half2v p0 = pk2(a.x, a.y), p1 = pk2(a.z, a.w);
    half2v p2 = pk2(b.x, b.y), p3 = pk2(b.z, b.w);
    xf[kk] = (half8v){p0[0], p0[1], p1[0], p1[1], p2[0], p2[1], p3[0], p3[1]};
  }

#pragma unroll
  for (int ht = 0; ht < 8; ++ht) {
    f32x4 acc;
    {
      float4 bb = *(const float4*)&b1v[16 * ht + 4 * q];
      acc = (f32x4){SCL * bb.x, SCL * bb.y, SCL * bb.z, SCL * bb.w};
    }
#pragma unroll
    for (int kk = 0; kk < 4; ++kk) {
      half8v wa = *(const half8v*)&W1T[(16 * ht + v) * YP + 32 * kk + 8 * q];
      acc = MFMA(wa, xf[kk], acc);
    }
    half2v zlo = pk2(tanh_s(acc[0]), tanh_s(acc[1]));
    half2v zhi = pk2(tanh_s(acc[2]), tanh_s(acc[3]));
    half4v z = {zlo[0], zlo[1], zhi[0], zhi[1]};
    // permuted store: p = 32q + 4ht + i
    *(half4v*)&THp[(size_t)(m0 + v) * NU + 32 * q + 4 * ht] = z;
  }
}

// ===================== K2: BARRIER-FREE recurrence, 1 wave per chain =====================
// 16 blocks x 64 thr. Each wave owns 16 batch rows AND the full 128-hidden
// state: 8 output tiles x 4 K-frags = 32 MFMA/step on its PRIVATE SIMD pipe
// (~512 cyc). The y-exchange is intra-wave (LDS write -> lgkmcnt -> read),
// eliminating s_barrier entirely (r4-r6 isolated ~300 cyc/step of barrier
// overhead that no VALU/LDS/pipe tuning could touch).
// K-frag streaming: write tile-pair kk -> lgkm -> read frag kk -> 8 MFMAs
// chained into accN, so next-step frag-0 MFMAs enter the pipe while frag-3
// MFMAs of this step still occupy it (keeps the pipe saturated across steps).
// y' = y-1 exchanged/stored (1-vector folded into b2 via colsum; k3 folds Wc).
__global__ __launch_bounds__(64, 1) void k2_recur(
    const _Float16* __restrict__ THp, const float* __restrict__ W2,
    const float* __restrict__ b2v, _Float16* __restrict__ Yws)
{
  __shared__ _Float16 Ybuf[2][2048];  // y' image in frag order, dbuf (4KB each)
  __shared__ float csb[NU];           // colsum(W2) redistribution

  const int L = (int)threadIdx.x & 63;
  const int v = L & 15, q = L >> 4;
  const int b0 = (int)blockIdx.x * 16;

  // ---- W2^T A-frags for ALL 8 tiles (scaled SCL): 128 VGPRs, prologue-only loads
  half8v w2f[8][4];
#pragma unroll
  for (int ht = 0; ht < 8; ++ht)
#pragma unroll
    for (int kk = 0; kk < 4; ++kk) {
      half8v h;
#pragma unroll
      for (int j = 0; j < 8; ++j)
        h[j] = (_Float16)(SCL * W2[(size_t)(32 * kk + 8 * q + j) * NU + 16 * ht + v]);
      w2f[ht][kk] = h;
    }

  // ---- colsum(W2) once per wave (coalesced), redistribute via LDS
  {
    float s0 = 0.f, s1 = 0.f;
    for (int k = 0; k < NU; ++k) {
      s0 += W2[(size_t)k * NU + L];
      s1 += W2[(size_t)k * NU + L + 64];
    }
    csb[L] = s0;
    csb[L + 64] = s1;
    asm volatile("s_waitcnt lgkmcnt(0)" ::: "memory");
  }

  // rA = r_0 = SCL*b2 (y_{-1}=0); b2f = SCL*(b2 + colsum) for y'-folded steps
  f32x4 rA[8], rB[8], b2f[8];
#pragma unroll
  for (int ht = 0; ht < 8; ++ht) {
    const int h0 = 16 * ht + 4 * q;
    float4 bb = *(const float4*)&b2v[h0];
    f32x4 cs4 = *(const f32x4*)&csb[h0];
    rA[ht] = (f32x4){SCL * bb.x, SCL * bb.y, SCL * bb.z, SCL * bb.w};
    b2f[ht] = rA[ht] + (f32x4){SCL * cs4[0], SCL * cs4[1], SCL * cs4[2], SCL * cs4[3]};
  }

  const _Float16* thp = THp + (size_t)(b0 + v) * NT * NU + 32 * q;
  _Float16* ypb = Yws + (size_t)(b0 + v) * NT * NU + 8 * q;
  // LDS write base (frag-order slot, r5-verified mapping with w->ht):
  _Float16* wr = &Ybuf[0][0] + v * 8 + 128 * (q >> 1) + 4 * (q & 1);
  const _Float16* rd = &Ybuf[0][0] + L * 8;

#define LOADTH(R_, T_)                                                        \
  {                                                                           \
    const _Float16* p_ = thp + (size_t)(T_) * NU;                             \
    R_[0] = *(const half8v*)(p_ + 0);                                         \
    R_[1] = *(const half8v*)(p_ + 8);                                         \
    R_[2] = *(const half8v*)(p_ + 16);                                        \
    R_[3] = *(const half8v*)(p_ + 24);                                        \
  }

  half8v thr0[4], thr1[4], thr2[4], thr3[4];  // 4-deep ring (~3 steps in flight)
  LOADTH(thr0, 0) LOADTH(thr1, 1) LOADTH(thr2, 2) LOADTH(thr3, 3)

  // RA_: racc being consumed (tanh); RN_: next racc being built (ping-pong).
#define RSTEP(T_, THR_, BUF_, RA_, RN_)                                       \
  {                                                                           \
    _Pragma("unroll")                                                         \
    for (int kk = 0; kk < 4; ++kk) {                                          \
      _Pragma("unroll")                                                       \
      for (int hh = 0; hh < 2; ++hh) {                                        \
        const int ht = 2 * kk + hh;                                           \
        const int j0 = 4 * hh;                                                \
        half2v ylo = pk2(ym1(RA_[ht][0], (float)THR_[kk][j0 + 0]),            \
                         ym1(RA_[ht][1], (float)THR_[kk][j0 + 1]));           \
        half2v yhi = pk2(ym1(RA_[ht][2], (float)THR_[kk][j0 + 2]),            \
                         ym1(RA_[ht][3], (float)THR_[kk][j0 + 3]));           \
        half4v y4 = {ylo[0], ylo[1], yhi[0], yhi[1]};                         \
        *(half4v*)(wr + (BUF_) * 2048 + kk * 512 + hh * 256) = y4;            \
      }                                                                       \
      asm volatile("s_waitcnt lgkmcnt(0)" ::: "memory");                      \
      half8v yf = *(const half8v*)(rd + (BUF_) * 2048 + kk * 512);            \
      *(half8v*)(ypb + (size_t)(T_) * NU + 32 * kk) = yf;                     \
      _Pragma("unroll")                                                       \
      for (int ht = 0; ht < 8; ++ht)                                          \
        RN_[ht] = MFMA(w2f[ht][kk], yf, (kk == 0) ? b2f[ht] : RN_[ht]);       \
    }                                                                         \
    {                                                                         \
      int tn = (T_) + 4; tn = tn < NT ? tn : NT - 1;                          \
      LOADTH(THR_, tn)                                                        \
    }                                                                         \
  }

#pragma unroll 1
  for (int t = 0; t < NT; t += 4) {
    RSTEP(t + 0, thr0, 0, rA, rB)
    RSTEP(t + 1, thr1, 1, rB, rA)
    RSTEP(t + 2, thr2, 0, rA, rB)
    RSTEP(t + 3, thr3, 1, rB, rA)
  }
#undef RSTEP
#undef LOADTH
}

// ===================== K3: out = Y' @ Wc + (bc + colsum(Wc)) =====================
__global__ __launch_bounds__(256, 1) void k3_head(
    const _Float16* __restrict__ Yp, const float* __restrict__ Wc,
    const float* __restrict__ bcv, float* __restrict__ out)
{
  __shared__ _Float16 WcT[NC * YP];  // Wc^T[c][k]
  __shared__ float bcp[NC];          // colsum(f16 Wc) for y'-fold
  const int tid = (int)threadIdx.x;
  for (int i = tid; i < NU * NC; i += 256) {
    int k = i >> 6, c = i & 63;
    WcT[c * YP + k] = (_Float16)Wc[i];
  }
  __syncthreads();
  if (tid < NC) {
    float s = 0.f;
    for (int k = 0; k < NU; ++k) s += (float)WcT[tid * YP + k];
    bcp[tid] = s;
  }
  __syncthreads();

  const int L = tid & 63, wv = tid >> 6;
  const int v = L & 15, q = L >> 4;
  const int m0 = (int)blockIdx.x * 64 + wv * 16;

  const _Float16* yr = Yp + (size_t)(m0 + v) * NU + 8 * q;
  half8v yf[4];
#pragma unroll
  for (int kk = 0; kk < 4; ++kk) yf[kk] = *(const half8v*)(yr + 32 * kk);

  float* op = out + (size_t)(m0 + v) * NC + 4 * q;
#pragma unroll
  for (int ct = 0; ct < 4; ++ct) {
    f32x4 acc;
    {
      float4 bb = *(const float4*)&bcv[16 * ct + 4 * q];
      f32x4 cq = *(const f32x4*)&bcp[16 * ct + 4 * q];
      acc = (f32x4){bb.x, bb.y, bb.z, bb.w} + cq;
    }
#pragma unroll
    for (int kk = 0; kk < 4; ++kk) {
      half8v wa = *(const half8v*)&WcT[(16 * ct + v) * YP + 32 * kk + 8 * q];
      acc = MFMA(wa, yf[kk], acc);
    }
    *(float4*)(op + 16 * ct) = (float4){acc[0], acc[1], acc[2], acc[3]};
  }
}

// ===================== fallback (round-2 kernel, no workspace) =====================
__device__ __forceinline__ float fast_tanh(float x) {
  float e = __expf(2.0f * x);
  return 1.0f - 2.0f / (e + 1.0f);
}
__device__ __forceinline__ float bcast(float val, int i) {
  return __builtin_bit_cast(float, __builtin_amdgcn_readlane(__builtin_bit_cast(int, val), i));
}

__global__ __launch_bounds__(256, 1) void rnn_fallback(
    const float* __restrict__ x, const float* __restrict__ W1,
    const float* __restrict__ b1v, const float* __restrict__ W2,
    const float* __restrict__ b2v, const float* __restrict__ Wc,
    const float* __restrict__ bcv, float* __restrict__ out)
{
  __shared__ float xring[16][ND];
  __shared__ float pH[2][4][NU];
  __shared__ float pR[2][4][NU];
  __shared__ float pC[2][4][NC];

  const int tid  = (int)threadIdx.x;
  const int lane = tid & 63;
  const int kg   = tid >> 6;
  const int b    = (int)blockIdx.x;
  const float4* xr4 = (const float4*)(x + (size_t)b * NT * ND);

  v2f w1f[32], w2f[32];
  float wcf[32];
#pragma unroll
  for (int i = 0; i < 32; ++i) {
    int k = kg * 32 + i;
    w1f[i] = (v2f){W1[k * NU + lane], W1[k * NU + lane + 64]};
    w2f[i] = (v2f){W2[k * NU + lane], W2[k * NU + lane + 64]};
    wcf[i] = Wc[k * NC + lane];
  }
  const float biasc = bcv[lane];
  float bias1 = 0.f, bias2 = 0.f;
  if (lane < 32) { bias1 = b1v[kg * 32 + lane]; bias2 = b2v[kg * 32 + lane]; }

  float4 stg = make_float4(0.f, 0.f, 0.f, 0.f);
  if (lane < 32) {
    float4 a0 = xr4[(kg + 0) * 32 + lane];
    float4 a1 = xr4[(kg + 4) * 32 + lane];
    ((float4*)xring[kg + 0])[lane] = a0;
    ((float4*)xring[kg + 4])[lane] = a1;
    stg = xr4[(kg + 8) * 32 + lane];
  }
  float yseg = 0.f;
  wg_barrier();

  for (int t = 0; t < NT; ++t) {
    const int pb = t & 1;
    v2f accH0 = {0.f, 0.f}, accH1 = {0.f, 0.f};
    const float4* xb = (const float4*)&xring[t & 15][kg * 32];
#pragma unroll
    for (int i = 0; i < 4; ++i) {
      float4 xa = xb[2 * i];
      float4 xc = xb[2 * i + 1];
      accH0 = w1f[8*i+0] * (v2f){xa.x, xa.x} + accH0;
      accH1 = w1f[8*i+1] * (v2f){xa.y, xa.y} + accH1;
      accH0 = w1f[8*i+2] * (v2f){xa.z, xa.z} + accH0;
      accH1 = w1f[8*i+3] * (v2f){xa.w, xa.w} + accH1;
      accH0 = w1f[8*i+4] * (v2f){xc.x, xc.x} + accH0;
      accH1 = w1f[8*i+5] * (v2f){xc.y, xc.y} + accH1;
      accH0 = w1f[8*i+6] * (v2f){xc.z, xc.z} + accH0;
      accH1 = w1f[8*i+7] * (v2f){xc.w, xc.w} + accH1;
    }
    v2f accH = accH0 + accH1;
    v2f accR0 = {0.f, 0.f}, accR1 = {0.f, 0.f};
    float accC0 = 0.f, accC1 = 0.f;
#pragma unroll
    for (int i = 0; i < 16; ++i) {
      float s0 = bcast(yseg, 2 * i);
      float s1 = bcast(yseg, 2 * i + 1);
      accR0 = w2f[2*i+0] * (v2f){s0, s0} + accR0;
      accR1 = w2f[2*i+1] * (v2f){s1, s1} + accR1;
      accC0 = fmaf(s0, wcf[2*i+0], accC0);
      accC1 = fmaf(s1, wcf[2*i+1], accC1);
    }
    v2f accR = accR0 + accR1;
    float accC = accC0 + accC1;

    pH[pb][kg][lane]      = accH.x;
    pH[pb][kg][lane + 64] = accH.y;
    pR[pb][kg][lane]      = accR.x;
    pR[pb][kg][lane + 64] = accR.y;
    pC[pb][kg][lane]      = accC;

    if (kg == (t & 3)) {
      if (lane < 32) {
        ((float4*)xring[(t + 8) & 15])[lane] = stg;
        int r = t + 12; r = (r < NT) ? r : (NT - 1);
        stg = xr4[r * 32 + lane];
      }
    }
    wg_barrier();
    if (lane < 32) {
      const int j = kg * 32 + lane;
      float hs = bias1, rs = bias2;
#pragma unroll
      for (int g = 0; g < 4; ++g) { hs += pH[pb][g][j]; rs += pR[pb][g][j]; }
      yseg = fast_tanh(hs) + fast_tanh(rs);
    }
    if (kg == ((t + 2) & 3) && t >= 1) {
      float cs = biasc;
#pragma unroll
      for (int g = 0; g < 4; ++g) cs += pC[pb][g][lane];
      out[((size_t)b * NT + (t - 1)) * NC + lane] = cs;
    }
  }
  float accC0 = 0.f, accC1 = 0.f;
#pragma unroll
  for (int i = 0; i < 16; ++i) {
    float s0 = bcast(yseg, 2 * i);
    float s1 = bcast(yseg, 2 * i + 1);
    accC0 = fmaf(s0, wcf[2*i+0], accC0);
    accC1 = fmaf(s1, wcf[2*i+1], accC1);
  }
  pC[0][kg][lane] = accC0 + accC1;
  wg_barrier();
  if (kg == 0) {
    float cs = biasc;
#pragma unroll
    for (int g = 0; g < 4; ++g) cs += pC[0][g][lane];
    out[((size_t)b * NT + (NT - 1)) * NC + lane] = cs;
  }
}

extern "C" void kernel_launch(void* const* d_in, const int* in_sizes, int n_in,
                              void* d_out, int out_size, void* d_ws, size_t ws_size,
                              hipStream_t stream) {
  (void)in_sizes; (void)n_in; (void)out_size;
  const float* x   = (const float*)d_in[0];
  const float* W1  = (const float*)d_in[1];
  const float* b1v = (const float*)d_in[2];
  const float* W2  = (const float*)d_in[3];
  const float* b2v = (const float*)d_in[4];
  const float* Wc  = (const float*)d_in[5];
  const float* bcv = (const float*)d_in[6];
  float* out = (float*)d_out;

  const size_t need = (size_t)NM * NU * 2 * 2;  // THp + Y', f16 each = 64 MiB
  if (ws_size >= need) {
    _Float16* THp = (_Float16*)d_ws;
    _Float16* Yw  = THp + (size_t)NM * NU;
    hipLaunchKernelGGL(k1_inproj, dim3(NM / 64), dim3(256), 0, stream, x, W1, b1v, THp);
    hipLaunchKernelGGL(k2_recur, dim3(NB / 16), dim3(64), 0, stream, THp, W2, b2v, Yw);
    hipLaunchKernelGGL(k3_head, dim3(NM / 64), dim3(256), 0, stream, Yw, Wc, bcv, out);
  } else {
    hipLaunchKernelGGL(rnn_fallback, dim3(NB), dim3(256), 0, stream,
                       x, W1, b1v, W2, b2v, Wc, bcv, out);
  }
}